// Round 2
// baseline (100.196 us; speedup 1.0000x reference)
//
#include <hip/hip_runtime.h>
#include <hip/hip_bf16.h>
#include <math.h>

#define N_ROWS 4096
#define DIM 512
#define T_TRIPLETS 65536

// ---------------------------------------------------------------------------
// Kernel A: sq[n] = sum_d x[n,d]^2.  One 64-lane wave per row.
// Row = 512 floats = 128 float4; each lane loads float4 at [lane] and [lane+64].
// ---------------------------------------------------------------------------
__global__ void __launch_bounds__(256) sq_kernel(const float* __restrict__ x,
                                                 float* __restrict__ sq) {
    int wave = (int)((blockIdx.x * blockDim.x + threadIdx.x) >> 6);
    int lane = (int)(threadIdx.x & 63);
    if (wave >= N_ROWS) return;
    const float4* row = (const float4*)(x + (size_t)wave * DIM);
    float4 a = row[lane];
    float4 b = row[lane + 64];
    float s = a.x * a.x + a.y * a.y + a.z * a.z + a.w * a.w
            + b.x * b.x + b.y * b.y + b.z * b.z + b.w * b.w;
#pragma unroll
    for (int off = 32; off >= 1; off >>= 1)
        s += __shfl_xor(s, off, 64);
    if (lane == 0) sq[wave] = s;
}

// ---------------------------------------------------------------------------
// Kernel B: one wave per triplet (i,j,k).
//   dij = x_i . x_j ; dik = x_i . x_k  (x_i loaded once, shared)
//   d_pos = max(sq_i + sq_j - 2 dij, 0); d_neg likewise with k
//   partial[t] = softplus(d_pos - d_neg), STABLE form:
//       softplus(t) = max(t,0) + log1p(exp(-|t|))
//   (mathematically identical to reference's log1p(exp(t)); avoids the fp32
//    overflow-to-inf that makes the harness's |inf-inf| = nan comparison fail)
// ---------------------------------------------------------------------------
__global__ void __launch_bounds__(256) triplet_kernel(const float* __restrict__ x,
                                                      const int* __restrict__ trip,
                                                      const float* __restrict__ sq,
                                                      float* __restrict__ partial) {
    int wave = (int)((blockIdx.x * blockDim.x + threadIdx.x) >> 6);
    int lane = (int)(threadIdx.x & 63);
    if (wave >= T_TRIPLETS) return;

    int i = trip[3 * wave + 0];
    int j = trip[3 * wave + 1];
    int k = trip[3 * wave + 2];

    const float4* ri = (const float4*)(x + (size_t)i * DIM);
    const float4* rj = (const float4*)(x + (size_t)j * DIM);
    const float4* rk = (const float4*)(x + (size_t)k * DIM);

    float4 a0 = ri[lane], a1 = ri[lane + 64];
    float4 b0 = rj[lane], b1 = rj[lane + 64];
    float4 c0 = rk[lane], c1 = rk[lane + 64];

    float dij = a0.x * b0.x + a0.y * b0.y + a0.z * b0.z + a0.w * b0.w
              + a1.x * b1.x + a1.y * b1.y + a1.z * b1.z + a1.w * b1.w;
    float dik = a0.x * c0.x + a0.y * c0.y + a0.z * c0.z + a0.w * c0.w
              + a1.x * c1.x + a1.y * c1.y + a1.z * c1.z + a1.w * c1.w;

#pragma unroll
    for (int off = 32; off >= 1; off >>= 1) {
        dij += __shfl_xor(dij, off, 64);
        dik += __shfl_xor(dik, off, 64);
    }

    if (lane == 0) {
        float si = sq[i], sj = sq[j], sk = sq[k];
        float d_pos = fmaxf(si + sj - 2.0f * dij, 0.0f);
        float d_neg = fmaxf(si + sk - 2.0f * dik, 0.0f);
        float t = d_pos - d_neg;
        // stable softplus
        float sp = fmaxf(t, 0.0f) + log1pf(expf(-fabsf(t)));
        partial[wave] = sp;
    }
}

// ---------------------------------------------------------------------------
// Kernel C: deterministic single-block reduction of 65536 partials, mean.
// ---------------------------------------------------------------------------
__global__ void __launch_bounds__(256) reduce_kernel(const float* __restrict__ partial,
                                                     float* __restrict__ out) {
    __shared__ float smem[256];
    float s = 0.0f;
    for (int t = (int)threadIdx.x; t < T_TRIPLETS; t += 256)
        s += partial[t];
    smem[threadIdx.x] = s;
    __syncthreads();
#pragma unroll
    for (int off = 128; off >= 1; off >>= 1) {
        if ((int)threadIdx.x < off) smem[threadIdx.x] += smem[threadIdx.x + off];
        __syncthreads();
    }
    if (threadIdx.x == 0) out[0] = smem[0] / (float)T_TRIPLETS;
}

extern "C" void kernel_launch(void* const* d_in, const int* in_sizes, int n_in,
                              void* d_out, int out_size, void* d_ws, size_t ws_size,
                              hipStream_t stream) {
    const float* x   = (const float*)d_in[0];
    const int*  trip = (const int*)d_in[1];
    float* out = (float*)d_out;

    // workspace layout: [0, 4096) floats: sq ; [4096, 4096+65536) floats: partials
    float* sq      = (float*)d_ws;
    float* partial = sq + N_ROWS;

    // A: row norms — 4096 waves = 1024 blocks x 256 threads
    sq_kernel<<<(N_ROWS * 64) / 256, 256, 0, stream>>>(x, sq);

    // B: one wave per triplet — 65536 waves = 16384 blocks x 256 threads
    triplet_kernel<<<(T_TRIPLETS * 64) / 256, 256, 0, stream>>>(x, trip, sq, partial);

    // C: final mean
    reduce_kernel<<<1, 256, 0, stream>>>(partial, out);
}

// Round 3
// 42.149 us; speedup vs baseline: 2.3772x; 2.3772x over previous
//
#include <hip/hip_runtime.h>
#include <hip/hip_bf16.h>
#include <math.h>

#define N_ROWS 4096
#define DIM 512
#define T_TRIPLETS 65536
#define B_BLOCKS (T_TRIPLETS / 4)   // 4 waves (=4 triplets) per 256-thread block

// ---------------------------------------------------------------------------
// Kernel A: sq[n] = sum_d x[n,d]^2.  One 64-lane wave per row.
// ---------------------------------------------------------------------------
__global__ void __launch_bounds__(256) sq_kernel(const float* __restrict__ x,
                                                 float* __restrict__ sq) {
    int wave = (int)((blockIdx.x * blockDim.x + threadIdx.x) >> 6);
    int lane = (int)(threadIdx.x & 63);
    if (wave >= N_ROWS) return;
    const float4* row = (const float4*)(x + (size_t)wave * DIM);
    float4 a = row[lane];
    float4 b = row[lane + 64];
    float s = a.x * a.x + a.y * a.y + a.z * a.z + a.w * a.w
            + b.x * b.x + b.y * b.y + b.z * b.z + b.w * b.w;
#pragma unroll
    for (int off = 32; off >= 1; off >>= 1)
        s += __shfl_xor(s, off, 64);
    if (lane == 0) sq[wave] = s;
}

// ---------------------------------------------------------------------------
// Kernel B: one wave per triplet; block of 4 waves reduces its 4 softplus
// values into ONE partial (deterministic fixed-order LDS reduce).
//   softplus(t) = max(t,0) + log1p(exp(-|t|))  -- stable form of reference's
//   log1p(exp(t)) (avoids fp32 overflow-to-inf).
// ---------------------------------------------------------------------------
__global__ void __launch_bounds__(256) triplet_kernel(const float* __restrict__ x,
                                                      const int* __restrict__ trip,
                                                      const float* __restrict__ sq,
                                                      float* __restrict__ blockPartial) {
    __shared__ float smem[4];
    int waveInBlock = (int)(threadIdx.x >> 6);
    int wave = (int)blockIdx.x * 4 + waveInBlock;   // triplet index
    int lane = (int)(threadIdx.x & 63);

    int i = trip[3 * wave + 0];
    int j = trip[3 * wave + 1];
    int k = trip[3 * wave + 2];

    const float4* ri = (const float4*)(x + (size_t)i * DIM);
    const float4* rj = (const float4*)(x + (size_t)j * DIM);
    const float4* rk = (const float4*)(x + (size_t)k * DIM);

    float4 a0 = ri[lane], a1 = ri[lane + 64];
    float4 b0 = rj[lane], b1 = rj[lane + 64];
    float4 c0 = rk[lane], c1 = rk[lane + 64];

    float dij = a0.x * b0.x + a0.y * b0.y + a0.z * b0.z + a0.w * b0.w
              + a1.x * b1.x + a1.y * b1.y + a1.z * b1.z + a1.w * b1.w;
    float dik = a0.x * c0.x + a0.y * c0.y + a0.z * c0.z + a0.w * c0.w
              + a1.x * c1.x + a1.y * c1.y + a1.z * c1.z + a1.w * c1.w;

#pragma unroll
    for (int off = 32; off >= 1; off >>= 1) {
        dij += __shfl_xor(dij, off, 64);
        dik += __shfl_xor(dik, off, 64);
    }

    if (lane == 0) {
        float si = sq[i], sj = sq[j], sk = sq[k];
        float d_pos = fmaxf(si + sj - 2.0f * dij, 0.0f);
        float d_neg = fmaxf(si + sk - 2.0f * dik, 0.0f);
        float t = d_pos - d_neg;
        smem[waveInBlock] = fmaxf(t, 0.0f) + log1pf(expf(-fabsf(t)));
    }
    __syncthreads();
    if (threadIdx.x == 0)
        blockPartial[blockIdx.x] = (smem[0] + smem[1]) + (smem[2] + smem[3]);
}

// ---------------------------------------------------------------------------
// Kernel C: deterministic single-block reduction of 16384 partials -> mean.
// 256 threads x 16 float4 coalesced loads.
// ---------------------------------------------------------------------------
__global__ void __launch_bounds__(256) reduce_kernel(const float* __restrict__ partial,
                                                     float* __restrict__ out) {
    __shared__ float smem[256];
    const float4* p4 = (const float4*)partial;
    float s = 0.0f;
#pragma unroll
    for (int it = 0; it < 16; ++it) {
        float4 v = p4[(int)threadIdx.x + 256 * it];
        s += (v.x + v.y) + (v.z + v.w);
    }
    smem[threadIdx.x] = s;
    __syncthreads();
#pragma unroll
    for (int off = 128; off >= 1; off >>= 1) {
        if ((int)threadIdx.x < off) smem[threadIdx.x] += smem[threadIdx.x + off];
        __syncthreads();
    }
    if (threadIdx.x == 0) out[0] = smem[0] / (float)T_TRIPLETS;
}

extern "C" void kernel_launch(void* const* d_in, const int* in_sizes, int n_in,
                              void* d_out, int out_size, void* d_ws, size_t ws_size,
                              hipStream_t stream) {
    const float* x   = (const float*)d_in[0];
    const int*  trip = (const int*)d_in[1];
    float* out = (float*)d_out;

    // workspace: [0,4096) sq ; [4096, 4096+16384) block partials
    float* sq      = (float*)d_ws;
    float* partial = sq + N_ROWS;

    sq_kernel<<<(N_ROWS * 64) / 256, 256, 0, stream>>>(x, sq);
    triplet_kernel<<<B_BLOCKS, 256, 0, stream>>>(x, trip, sq, partial);
    reduce_kernel<<<1, 256, 0, stream>>>(partial, out);
}

// Round 4
// 35.571 us; speedup vs baseline: 2.8168x; 1.1849x over previous
//
#include <hip/hip_runtime.h>
#include <hip/hip_bf16.h>
#include <math.h>

#define N_ROWS 4096
#define DIM 512
#define T_TRIPLETS 65536
#define B_BLOCKS (T_TRIPLETS / 4)   // 4 waves (=4 triplets) per 256-thread block

// round-to-nearest-even f32 -> bf16 bits (inputs are finite gaussians; no NaN path)
static __device__ inline unsigned short f2bf(float f) {
    unsigned u = __float_as_uint(f);
    unsigned r = (u + 0x7fffu + ((u >> 16) & 1u)) >> 16;
    return (unsigned short)r;
}

// ---------------------------------------------------------------------------
// Kernel A: per row — sq[n] = sum x[n,:]^2 (fp32), and xb[n,:] = bf16(x[n,:]).
// One wave per row; lane handles elems [4L..4L+3] and [256+4L..256+4L+3].
// ---------------------------------------------------------------------------
__global__ void __launch_bounds__(256) prep_kernel(const float* __restrict__ x,
                                                   float* __restrict__ sq,
                                                   unsigned short* __restrict__ xb) {
    int wave = (int)((blockIdx.x * blockDim.x + threadIdx.x) >> 6);
    int lane = (int)(threadIdx.x & 63);
    if (wave >= N_ROWS) return;
    const float4* row = (const float4*)(x + (size_t)wave * DIM);
    float4 a = row[lane];
    float4 b = row[lane + 64];

    ushort4* brow = (ushort4*)(xb + (size_t)wave * DIM);
    ushort4 pa, pb;
    pa.x = f2bf(a.x); pa.y = f2bf(a.y); pa.z = f2bf(a.z); pa.w = f2bf(a.w);
    pb.x = f2bf(b.x); pb.y = f2bf(b.y); pb.z = f2bf(b.z); pb.w = f2bf(b.w);
    brow[lane]      = pa;
    brow[lane + 64] = pb;

    float s = a.x * a.x + a.y * a.y + a.z * a.z + a.w * a.w
            + b.x * b.x + b.y * b.y + b.z * b.z + b.w * b.w;
#pragma unroll
    for (int off = 32; off >= 1; off >>= 1)
        s += __shfl_xor(s, off, 64);
    if (lane == 0) sq[wave] = s;
}

// unpack a uint holding two bf16 (lo=elem0, hi=elem1) into two f32
static __device__ inline void unpk(unsigned u, float& lo, float& hi) {
    lo = __uint_as_float(u << 16);
    hi = __uint_as_float(u & 0xffff0000u);
}

// ---------------------------------------------------------------------------
// Kernel B: one wave per triplet (i,j,k), bf16 rows (1 KB each; one uint4/lane).
//   dij = x_i.x_j ; dik = x_i.x_k  in fp32 accumulation.
//   partial-per-block = sum of 4 waves' softplus(d_pos - d_neg), stable form.
// ---------------------------------------------------------------------------
__global__ void __launch_bounds__(256) triplet_kernel(const unsigned short* __restrict__ xb,
                                                      const int* __restrict__ trip,
                                                      const float* __restrict__ sq,
                                                      float* __restrict__ blockPartial) {
    __shared__ float smem[4];
    int waveInBlock = (int)(threadIdx.x >> 6);
    int wave = (int)blockIdx.x * 4 + waveInBlock;   // triplet index
    int lane = (int)(threadIdx.x & 63);

    int i = trip[3 * wave + 0];
    int j = trip[3 * wave + 1];
    int k = trip[3 * wave + 2];

    const uint4* ri = (const uint4*)(xb + (size_t)i * DIM);
    const uint4* rj = (const uint4*)(xb + (size_t)j * DIM);
    const uint4* rk = (const uint4*)(xb + (size_t)k * DIM);

    uint4 ua = ri[lane];
    uint4 ub = rj[lane];
    uint4 uc = rk[lane];

    float dij = 0.0f, dik = 0.0f;
    unsigned aw[4] = {ua.x, ua.y, ua.z, ua.w};
    unsigned bw[4] = {ub.x, ub.y, ub.z, ub.w};
    unsigned cw[4] = {uc.x, uc.y, uc.z, uc.w};
#pragma unroll
    for (int q = 0; q < 4; ++q) {
        float a0, a1, b0, b1, c0, c1;
        unpk(aw[q], a0, a1);
        unpk(bw[q], b0, b1);
        unpk(cw[q], c0, c1);
        dij = fmaf(a0, b0, dij); dij = fmaf(a1, b1, dij);
        dik = fmaf(a0, c0, dik); dik = fmaf(a1, c1, dik);
    }

#pragma unroll
    for (int off = 32; off >= 1; off >>= 1) {
        dij += __shfl_xor(dij, off, 64);
        dik += __shfl_xor(dik, off, 64);
    }

    if (lane == 0) {
        float si = sq[i], sj = sq[j], sk = sq[k];
        float d_pos = fmaxf(si + sj - 2.0f * dij, 0.0f);
        float d_neg = fmaxf(si + sk - 2.0f * dik, 0.0f);
        float t = d_pos - d_neg;
        smem[waveInBlock] = fmaxf(t, 0.0f) + log1pf(expf(-fabsf(t)));
    }
    __syncthreads();
    if (threadIdx.x == 0)
        blockPartial[blockIdx.x] = (smem[0] + smem[1]) + (smem[2] + smem[3]);
}

// ---------------------------------------------------------------------------
// Kernel C: deterministic single-block reduction of 16384 partials -> mean.
// ---------------------------------------------------------------------------
__global__ void __launch_bounds__(256) reduce_kernel(const float* __restrict__ partial,
                                                     float* __restrict__ out) {
    __shared__ float smem[256];
    const float4* p4 = (const float4*)partial;
    float s = 0.0f;
#pragma unroll
    for (int it = 0; it < 16; ++it) {
        float4 v = p4[(int)threadIdx.x + 256 * it];
        s += (v.x + v.y) + (v.z + v.w);
    }
    smem[threadIdx.x] = s;
    __syncthreads();
#pragma unroll
    for (int off = 128; off >= 1; off >>= 1) {
        if ((int)threadIdx.x < off) smem[threadIdx.x] += smem[threadIdx.x + off];
        __syncthreads();
    }
    if (threadIdx.x == 0) out[0] = smem[0] / (float)T_TRIPLETS;
}

extern "C" void kernel_launch(void* const* d_in, const int* in_sizes, int n_in,
                              void* d_out, int out_size, void* d_ws, size_t ws_size,
                              hipStream_t stream) {
    const float* x   = (const float*)d_in[0];
    const int*  trip = (const int*)d_in[1];
    float* out = (float*)d_out;

    // workspace layout (floats): [0,4096) sq ; [4096, 20480) block partials ;
    // then bf16 x copy (4096*512 ushort = 4 MB), 16B-aligned (offset 81920 B).
    float* sq      = (float*)d_ws;
    float* partial = sq + N_ROWS;
    unsigned short* xb = (unsigned short*)(partial + B_BLOCKS);

    prep_kernel<<<(N_ROWS * 64) / 256, 256, 0, stream>>>(x, sq, xb);
    triplet_kernel<<<B_BLOCKS, 256, 0, stream>>>(xb, trip, sq, partial);
    reduce_kernel<<<1, 256, 0, stream>>>(partial, out);
}